// Round 6
// baseline (952.886 us; speedup 1.0000x reference)
//
#include <hip/hip_runtime.h>
#include <hip/hip_cooperative_groups.h>

namespace cg = cooperative_groups;

#define N_NODES 100000
#define N_EDGES 1600000
#define D 64
#define NB 782                 // ceil(100000/128) dst-buckets of 128 nodes
#define CAP 3072               // slab slots per bucket (mean 2048, sigma~45)
#define RSH 14                 // src-range shift: range = src>>14 in 0..6

// cooperative mega-kernel config: 240 blocks x 1024 thr.
// Cooperative capacity = 256 CUs x 1 block/CU (runtime occupancy uses the
// 64KB shared-mem API cap; our 62.7KB -> 1 block/CU). 240 < 256 with margin.
#define GRID 240
#define EPB 8192               // edges per partition chunk (round-0 proven)
#define NPART ((N_EDGES + EPB - 1) / EPB)   // 196
#define SMEM_BYTES 62656

// fallback (round-4 proven) partition config
#define EPBF 4096
#define NPBF ((N_EDGES + EPBF - 1) / EPBF)  // 391

typedef unsigned short ushort_t;
typedef unsigned int uint_t;

__device__ __forceinline__ ushort_t f2bf(float f) {
    uint_t u = __float_as_uint(f);
    u += 0x7FFF + ((u >> 16) & 1);          // round-nearest-even
    return (ushort_t)(u >> 16);
}

// ---------- 8-lane all-reduce on the VALU pipe (DPP, no DS ops) ----------
template<int CTRL>
__device__ __forceinline__ float fadd_dpp(float x) {
    const int r = __builtin_amdgcn_update_dpp(0, __float_as_int(x), CTRL, 0xF, 0xF, true);
    return x + __int_as_float(r);
}
__device__ __forceinline__ float red8(float p) {
    p = fadd_dpp<0xB1>(p);    // quad_perm [1,0,3,2]  : xor 1
    p = fadd_dpp<0x4E>(p);    // quad_perm [2,3,0,1]  : xor 2
    p = fadd_dpp<0x141>(p);   // row_half_mirror      : xor within 8
    return p;
}

// cvt 8 bf16 (uint4) -> g[8] fp32, and dot vs h[8]
__device__ __forceinline__ float cvt_dot(const uint4 u, const float* __restrict__ h,
                                         float* __restrict__ g) {
    g[0] = __uint_as_float(u.x << 16); g[1] = __uint_as_float(u.x & 0xFFFF0000u);
    g[2] = __uint_as_float(u.y << 16); g[3] = __uint_as_float(u.y & 0xFFFF0000u);
    g[4] = __uint_as_float(u.z << 16); g[5] = __uint_as_float(u.z & 0xFFFF0000u);
    g[6] = __uint_as_float(u.w << 16); g[7] = __uint_as_float(u.w & 0xFFFF0000u);
    float p = 0.f;
#pragma unroll
    for (int k = 0; k < 8; ++k) p += g[k] * h[k];
    return p;
}

// ================= cooperative mega-kernel =================
// phase 1: repack feat->bf16 (grid-stride) + partition (verbatim round-0
//          1024-thread body, zero-based gcur)       | grid.sync
// phase 2: fused SDDMM+SpMM, grid-stride over the 782 buckets; one bucket =
//          128 node-slots x 8 lanes = exactly 1024 threads | grid.sync
// phase 3: in-place GEMM out = out @ W^T, 128-row tiles (round-0 K4 body at
//          2 rows/thread)
// NO register state crosses a phase boundary (r1/r2 spill lesson). LDS is a
// 62656-byte union re-carved per phase; phases separated by grid barriers.
__global__ __launch_bounds__(1024) void mega(
        const float* __restrict__ feat, ushort_t* __restrict__ featb,
        const int* __restrict__ esrc, const int* __restrict__ edst,
        int* __restrict__ gcur, int* __restrict__ slab,
        float* __restrict__ out, const float* __restrict__ W) {
    cg::grid_group grid = cg::this_grid();
    __shared__ __align__(16) char smem[SMEM_BYTES];
    const int t = threadIdx.x;
    const int bid = blockIdx.x;

    // ---- phase 1a: repack feat -> bf16, 16-float chunks, grid-stride ----
    {
        const int gtid = bid * 1024 + t;
        for (int c = gtid; c < N_NODES * D / 16; c += GRID * 1024) {
            const float4* f4 = (const float4*)(feat + c * 16);
            ushort4* o4 = (ushort4*)(featb + c * 16);
#pragma unroll
            for (int j = 0; j < 4; ++j) {
                const float4 v = f4[j];
                o4[j] = make_ushort4(f2bf(v.x), f2bf(v.y), f2bf(v.z), f2bf(v.w));
            }
        }
    }
    // ---- phase 1b: partition chunk bid (round-0 body; gcur zero-based) ----
    if (bid < NPART) {
        int*      stage = (int*)(smem);                  // 32768 B
        ushort_t* bkt16 = (ushort_t*)(smem + 32768);     // 16384 B
        int*      cnt   = (int*)(smem + 49152);          //  3136 B
        int*      cur   = (int*)(smem + 52288);          //  3136 B
        int*      gb    = (int*)(smem + 55424);          //  3136 B
        int*      s     = (int*)(smem + 58560);          //  4096 B -> 62656
        const int base = bid * EPB;
        const int n = min(EPB, N_EDGES - base);

        if (t < NB) cnt[t] = 0;
        __syncthreads();
        for (int i = t; i < n; i += 1024)
            atomicAdd(&cnt[edst[base + i] >> 7], 1);
        __syncthreads();
        const int v = (t < NB) ? cnt[t] : 0;
        s[t] = v;
        __syncthreads();
        for (int off = 1; off < 1024; off <<= 1) {
            const int x = (t >= off) ? s[t - off] : 0;
            __syncthreads();
            s[t] += x;
            __syncthreads();
        }
        if (t < NB) {
            const int excl = s[t] - v;          // exclusive prefix
            cur[t] = excl;
            gb[t] = t * CAP + (v ? atomicAdd(&gcur[t], v) : 0) - excl;
        }
        __syncthreads();
        for (int i = t; i < n; i += 1024) {     // coalesced re-read (L2-hot)
            const int d = edst[base + i];
            const int bkt = d >> 7;
            const int pos = atomicAdd(&cur[bkt], 1);
            stage[pos] = ((d & 127) << 17) | esrc[base + i];
            bkt16[pos] = (ushort_t)bkt;
        }
        __syncthreads();
        for (int i = t; i < n; i += 1024) {     // coalesced segment writes
            const int bkt = bkt16[i];
            const int gp = gb[bkt] + i;
            if (gp < (bkt + 1) * CAP)           // overflow guard
                slab[gp] = stage[i];
        }
    }
    __threadfence();
    grid.sync();        // featb + slab + gcur visible grid-wide

    // ---- phase 2: fused SDDMM + SpMM, grid-stride over buckets ----
    {
        int* seA    = (int*)(smem);                  // 12288 B
        int* seB    = (int*)(smem + 12288);          // 12288 B
        int* cnt    = (int*)(smem + 24576);          //  4096 B
        int* cur    = (int*)(smem + 28672);          //  4096 B
        int* rowoff = (int*)(smem + 32768);          //   516 B
        int* s      = (int*)(smem + 33296);          //  4096 B -> 37392
        const float4* feat4 = (const float4*)feat;
        const uint4* featb4 = (const uint4*)featb;
        float4* neigh4 = (float4*)out;

        for (int bk = bid; bk < NB; bk += GRID) {
            const int nbase = bk << 7;
            const int nb_nodes = min(128, N_NODES - nbase);
            const int sbase = bk * CAP;
            const int ne = min(gcur[bk], CAP);

            for (int i = t; i < ne; i += 1024) seA[i] = slab[sbase + i];
            cnt[t] = 0;
            __syncthreads();
            for (int i = t; i < ne; i += 1024) {
                const int pk = seA[i];
                atomicAdd(&cnt[((pk >> 17) << 3) | ((pk & 0x1FFFF) >> RSH)], 1);
            }
            __syncthreads();
            const int v = cnt[t];
            s[t] = v;
            __syncthreads();
            for (int off = 1; off < 1024; off <<= 1) {
                const int x = (t >= off) ? s[t - off] : 0;
                __syncthreads();
                s[t] += x;
                __syncthreads();
            }
            cur[t] = s[t] - v;                   // exclusive prefix per key
            __syncthreads();
            if (t < 128) rowoff[t] = cur[t << 3];
            if (t == 0) rowoff[128] = ne;
            __syncthreads();
            for (int i = t; i < ne; i += 1024) {
                const int pk = seA[i];
                const int key = ((pk >> 17) << 3) | ((pk & 0x1FFFF) >> RSH);
                const int pos = atomicAdd(&cur[key], 1);
                seB[pos] = pk & 0x1FFFF;
            }
            __syncthreads();

            const int slot = t >> 3;             // 128 node-slots per block
            const int l = t & 7;                 // lane owns dims 8l..8l+7
            if (slot < nb_nodes) {               // no barriers inside: safe
                const int nidx = nbase + slot;
                float h[8];
                {
                    const float4 ha = feat4[nidx * 16 + 2 * l];
                    const float4 hb = feat4[nidx * 16 + 2 * l + 1];
                    h[0] = ha.x; h[1] = ha.y; h[2] = ha.z; h[3] = ha.w;
                    h[4] = hb.x; h[5] = hb.y; h[6] = hb.z; h[7] = hb.w;
                }
                float acc[8];
#pragma unroll
                for (int k = 0; k < 8; ++k) acc[k] = 0.f;

                int e = rowoff[slot];
                const int e1 = rowoff[slot + 1];
                for (; e + 3 < e1; e += 4) {
                    const int s0 = seB[e], s1 = seB[e + 1];
                    const int s2 = seB[e + 2], s3 = seB[e + 3];
                    const uint4 u0 = featb4[s0 * 8 + l];   // 4 gathers in flight
                    const uint4 u1 = featb4[s1 * 8 + l];
                    const uint4 u2 = featb4[s2 * 8 + l];
                    const uint4 u3 = featb4[s3 * 8 + l];
                    float g0[8], g1[8], g2[8], g3[8];
                    float p0 = cvt_dot(u0, h, g0);
                    float p1 = cvt_dot(u1, h, g1);
                    float p2 = cvt_dot(u2, h, g2);
                    float p3 = cvt_dot(u3, h, g3);
                    p0 = red8(p0); p1 = red8(p1); p2 = red8(p2); p3 = red8(p3);
#pragma unroll
                    for (int k = 0; k < 8; ++k)
                        acc[k] += g0[k] * p0 + g1[k] * p1 + g2[k] * p2 + g3[k] * p3;
                }
                for (; e < e1; ++e) {
                    const uint4 u0 = featb4[seB[e] * 8 + l];
                    float g0[8];
                    float p0 = red8(cvt_dot(u0, h, g0));
#pragma unroll
                    for (int k = 0; k < 8; ++k) acc[k] += g0[k] * p0;
                }
                neigh4[nidx * 16 + 2 * l]     = make_float4(acc[0], acc[1], acc[2], acc[3]);
                neigh4[nidx * 16 + 2 * l + 1] = make_float4(acc[4], acc[5], acc[6], acc[7]);
            }
            __syncthreads();    // protect seA/cnt of next bucket iteration
        }
    }
    __threadfence();
    grid.sync();        // neigh complete grid-wide

    // ---- phase 3: in-place GEMM out = out @ W^T, 128-row tiles ----
    {
        float (*WT)[68]  = (float(*)[68])(smem);           // 17408 B
        float (*nT)[132] = (float(*)[132])(smem + 17408);  // 33792 B -> 51200
        const float4* W4 = (const float4*)W;
        {   // stage W^T once (1024 threads x 1 float4 = whole 64x64 W)
            const float4 w = W4[t];
            const int o = t >> 4;
            const int i4 = (t & 15) * 4;
            WT[i4 + 0][o] = w.x;
            WT[i4 + 1][o] = w.y;
            WT[i4 + 2][o] = w.z;
            WT[i4 + 3][o] = w.w;
        }
        for (int tile = bid; tile < NB; tile += GRID) {
            const int rbase = tile << 7;
            const int rows = min(128, N_NODES - rbase);
            const float4* O4 = (const float4*)(out + (long)rbase * D);
            __syncthreads();                // WT ready / prev-tile reads done
#pragma unroll
            for (int j = 0; j < 2; ++j) {   // stage tile transposed
                const int f = t + j * 1024;
                const int r = f >> 4;
                const int i4 = (f & 15) * 4;
                if (r < rows) {
                    const float4 x = O4[f];
                    nT[i4 + 0][r] = x.x;
                    nT[i4 + 1][r] = x.y;
                    nT[i4 + 2][r] = x.z;
                    nT[i4 + 3][r] = x.w;
                }
            }
            __syncthreads();
            const int c4 = (t & 15) * 4;
            const int r0 = (t >> 4) * 2;
            float a00 = 0.f, a01 = 0.f, a02 = 0.f, a03 = 0.f;
            float a10 = 0.f, a11 = 0.f, a12 = 0.f, a13 = 0.f;
            for (int i = 0; i < 64; ++i) {
                const float4 w = *(const float4*)&WT[i][c4];
                const float x0 = nT[i][r0];
                const float x1 = nT[i][r0 + 1];
                a00 += x0 * w.x; a01 += x0 * w.y; a02 += x0 * w.z; a03 += x0 * w.w;
                a10 += x1 * w.x; a11 += x1 * w.y; a12 += x1 * w.z; a13 += x1 * w.w;
            }
            if (r0 < rows)
                *(float4*)&out[(long)(rbase + r0) * D + c4] =
                    make_float4(a00, a01, a02, a03);
            if (r0 + 1 < rows)
                *(float4*)&out[(long)(rbase + r0 + 1) * D + c4] =
                    make_float4(a10, a11, a12, a13);
        }
    }
}

// ================= fallback: round-4 proven 3-kernel pipeline =================
__global__ __launch_bounds__(512) void repack_partition(
        const float* __restrict__ feat, ushort_t* __restrict__ featb,
        const int* __restrict__ esrc, const int* __restrict__ edst,
        int* __restrict__ gcur, int* __restrict__ slab) {
    __shared__ int stage[EPBF];
    __shared__ ushort_t bkt16[EPBF];
    __shared__ int cnt[1024];
    __shared__ int cur[1024];
    __shared__ int gb[NB];
    __shared__ int s[512];
    const int t = threadIdx.x;
    const int b = blockIdx.x;
    const int tid = b * 512 + t;

#pragma unroll
    for (int g = 0; g < 2; ++g) {
        const int base = (tid * 2 + g) * 16;
        if (base < N_NODES * D) {
            const float4* f4 = (const float4*)(feat + base);
            ushort4* o4 = (ushort4*)(featb + base);
#pragma unroll
            for (int j = 0; j < 4; ++j) {
                const float4 v = f4[j];
                o4[j] = make_ushort4(f2bf(v.x), f2bf(v.y), f2bf(v.z), f2bf(v.w));
            }
        }
    }

    const int base = b * EPBF;
    const int n = min(EPBF, N_EDGES - base);

    cnt[t] = 0; cnt[t + 512] = 0;
    __syncthreads();
    for (int i = t; i < n; i += 512)
        atomicAdd(&cnt[edst[base + i] >> 7], 1);
    __syncthreads();
    const int v0 = cnt[2 * t], v1 = cnt[2 * t + 1];
    const int sum = v0 + v1;
    s[t] = sum;
    __syncthreads();
    for (int off = 1; off < 512; off <<= 1) {
        const int x = (t >= off) ? s[t - off] : 0;
        __syncthreads();
        s[t] += x;
        __syncthreads();
    }
    const int excl = s[t] - sum;
    cur[2 * t] = excl;
    cur[2 * t + 1] = excl + v0;
    __syncthreads();
    for (int i = t; i < NB; i += 512) {
        const int c = cnt[i];
        gb[i] = i * CAP + (c ? atomicAdd(&gcur[i], c) : 0) - cur[i];
    }
    __syncthreads();
    for (int i = t; i < n; i += 512) {
        const int d = edst[base + i];
        const int bkt = d >> 7;
        const int pos = atomicAdd(&cur[bkt], 1);
        stage[pos] = ((d & 127) << 17) | esrc[base + i];
        bkt16[pos] = (ushort_t)bkt;
    }
    __syncthreads();
    for (int i = t; i < n; i += 512) {
        const int bkt = bkt16[i];
        const int gp = gb[bkt] + i;
        if (gp < (bkt + 1) * CAP)
            slab[gp] = stage[i];
    }
}

__global__ __launch_bounds__(512) void fused_spmm(const float4* __restrict__ feat4,
                                                  const uint4* __restrict__ featb4,
                                                  const int* __restrict__ slab,
                                                  const int* __restrict__ gcur,
                                                  float4* __restrict__ neigh4) {
    __shared__ int seA[CAP];
    __shared__ int seB[CAP];
    __shared__ int cnt[1024];
    __shared__ int cur[1024];
    __shared__ int rowoff[129];
    __shared__ int s[512];
    const int t = threadIdx.x;
    const int b = blockIdx.x;
    const int nbase = b << 7;
    const int nb_nodes = min(128, N_NODES - nbase);
    const int sbase = b * CAP;
    const int ne = min(gcur[b], CAP);

    for (int i = t; i < ne; i += 512) seA[i] = slab[sbase + i];
    cnt[t] = 0; cnt[t + 512] = 0;
    __syncthreads();
    for (int i = t; i < ne; i += 512) {
        const int pk = seA[i];
        atomicAdd(&cnt[((pk >> 17) << 3) | ((pk & 0x1FFFF) >> RSH)], 1);
    }
    __syncthreads();
    const int v0 = cnt[2 * t], v1 = cnt[2 * t + 1];
    const int sum = v0 + v1;
    s[t] = sum;
    __syncthreads();
    for (int off = 1; off < 512; off <<= 1) {
        const int x = (t >= off) ? s[t - off] : 0;
        __syncthreads();
        s[t] += x;
        __syncthreads();
    }
    const int excl = s[t] - sum;
    cur[2 * t] = excl;
    cur[2 * t + 1] = excl + v0;
    __syncthreads();
    if (t < 128) rowoff[t] = cur[t << 3];
    if (t == 0) rowoff[128] = ne;
    __syncthreads();
    for (int i = t; i < ne; i += 512) {
        const int pk = seA[i];
        const int key = ((pk >> 17) << 3) | ((pk & 0x1FFFF) >> RSH);
        const int pos = atomicAdd(&cur[key], 1);
        seB[pos] = pk & 0x1FFFF;
    }
    __syncthreads();

    const int slot = t >> 3;
    const int l = t & 7;
#pragma unroll
    for (int ln0 = 0; ln0 < 128; ln0 += 64) {
        const int ln = ln0 + slot;
        if (ln >= nb_nodes) continue;
        const int nidx = nbase + ln;
        float h[8];
        {
            const float4 ha = feat4[nidx * 16 + 2 * l];
            const float4 hb = feat4[nidx * 16 + 2 * l + 1];
            h[0] = ha.x; h[1] = ha.y; h[2] = ha.z; h[3] = ha.w;
            h[4] = hb.x; h[5] = hb.y; h[6] = hb.z; h[7] = hb.w;
        }
        float acc[8];
#pragma unroll
        for (int k = 0; k < 8; ++k) acc[k] = 0.f;

        int e = rowoff[ln];
        const int e1 = rowoff[ln + 1];
        for (; e + 3 < e1; e += 4) {
            const int s0 = seB[e], s1 = seB[e + 1], s2 = seB[e + 2], s3 = seB[e + 3];
            const uint4 u0 = featb4[s0 * 8 + l];
            const uint4 u1 = featb4[s1 * 8 + l];
            const uint4 u2 = featb4[s2 * 8 + l];
            const uint4 u3 = featb4[s3 * 8 + l];
            float g0[8], g1[8], g2[8], g3[8];
            float p0 = cvt_dot(u0, h, g0);
            float p1 = cvt_dot(u1, h, g1);
            float p2 = cvt_dot(u2, h, g2);
            float p3 = cvt_dot(u3, h, g3);
            p0 = red8(p0); p1 = red8(p1); p2 = red8(p2); p3 = red8(p3);
#pragma unroll
            for (int k = 0; k < 8; ++k)
                acc[k] += g0[k] * p0 + g1[k] * p1 + g2[k] * p2 + g3[k] * p3;
        }
        for (; e < e1; ++e) {
            const uint4 u0 = featb4[seB[e] * 8 + l];
            float g0[8];
            float p0 = red8(cvt_dot(u0, h, g0));
#pragma unroll
            for (int k = 0; k < 8; ++k) acc[k] += g0[k] * p0;
        }
        neigh4[nidx * 16 + 2 * l]     = make_float4(acc[0], acc[1], acc[2], acc[3]);
        neigh4[nidx * 16 + 2 * l + 1] = make_float4(acc[4], acc[5], acc[6], acc[7]);
    }
}

__global__ __launch_bounds__(256) void gemm_inplace(float* __restrict__ out,
                                                    const float* __restrict__ W) {
    __shared__ float WT[64][68];
    __shared__ float nT[64][132];
    const int t = threadIdx.x;

    const float4* W4 = (const float4*)W;
#pragma unroll
    for (int j = 0; j < 4; ++j) {
        const int f = t + j * 256;
        const int o = f >> 4;
        const int i4 = (f & 15) * 4;
        const float4 w = W4[f];
        WT[i4 + 0][o] = w.x;
        WT[i4 + 1][o] = w.y;
        WT[i4 + 2][o] = w.z;
        WT[i4 + 3][o] = w.w;
    }

    const int base = blockIdx.x * 128;
    const int rows = min(128, N_NODES - base);
    const float4* O4 = (const float4*)(out + (long)base * D);
#pragma unroll
    for (int j = 0; j < 8; ++j) {
        const int f = t + j * 256;
        const int r = f >> 4;
        const int i4 = (f & 15) * 4;
        if (r < rows) {
            const float4 x = O4[f];
            nT[i4 + 0][r] = x.x;
            nT[i4 + 1][r] = x.y;
            nT[i4 + 2][r] = x.z;
            nT[i4 + 3][r] = x.w;
        }
    }
    __syncthreads();

    const int c4 = (t & 15) * 4;
    const int r0 = (t >> 4) * 8;
    float acc[8][4];
#pragma unroll
    for (int r = 0; r < 8; ++r)
#pragma unroll
        for (int c = 0; c < 4; ++c) acc[r][c] = 0.f;

    for (int i = 0; i < 64; ++i) {
        const float4 w = *(const float4*)&WT[i][c4];
        const float4 ra = *(const float4*)&nT[i][r0];
        const float4 rb = *(const float4*)&nT[i][r0 + 4];
        const float wv[4] = {w.x, w.y, w.z, w.w};
        const float rv[8] = {ra.x, ra.y, ra.z, ra.w, rb.x, rb.y, rb.z, rb.w};
#pragma unroll
        for (int r = 0; r < 8; ++r)
#pragma unroll
            for (int c = 0; c < 4; ++c) acc[r][c] += rv[r] * wv[c];
    }

#pragma unroll
    for (int r = 0; r < 8; ++r) {
        const int rr = r0 + r;
        if (rr < rows)
            *(float4*)&out[(long)(base + rr) * D + c4] =
                make_float4(acc[r][0], acc[r][1], acc[r][2], acc[r][3]);
    }
}

extern "C" void kernel_launch(void* const* d_in, const int* in_sizes, int n_in,
                              void* d_out, int out_size, void* d_ws, size_t ws_size,
                              hipStream_t stream) {
    const float* feat = (const float*)d_in[0];
    const int*   esrc = (const int*)d_in[1];
    const int*   edst = (const int*)d_in[2];
    const float* W    = (const float*)d_in[3];
    float* out = (float*)d_out;

    char* ws = (char*)d_ws;
    ushort_t* featb = (ushort_t*)(ws);                       // 12.8 MB
    int* slab = (int*)(ws + 12800000);                       // NB*CAP*4 = 9.61 MB
    int* gcur = (int*)(ws + 12800000 + (size_t)NB * CAP * 4);// 3.1 KB

    hipMemsetAsync(gcur, 0, NB * sizeof(int), stream);       // zero-based counts

    void* args[] = {(void*)&feat, (void*)&featb, (void*)&esrc, (void*)&edst,
                    (void*)&gcur, (void*)&slab, (void*)&out, (void*)&W};
    const hipError_t err = hipLaunchCooperativeKernel(
        (const void*)mega, dim3(GRID), dim3(1024), args, 0, stream);
    if (err != hipSuccess) {
        (void)hipGetLastError();                             // clear sticky error
        // proven round-4 pipeline (174.8 us)
        repack_partition<<<NPBF, 512, 0, stream>>>(feat, featb, esrc, edst,
                                                   gcur, slab);
        fused_spmm<<<NB, 512, 0, stream>>>((const float4*)feat,
                                           (const uint4*)featb,
                                           slab, gcur, (float4*)out);
        gemm_inplace<<<(N_NODES + 127) / 128, 256, 0, stream>>>(out, W);
    }
}

// Round 7
// 162.762 us; speedup vs baseline: 5.8545x; 5.8545x over previous
//
#include <hip/hip_runtime.h>

#define N_NODES 100000
#define N_EDGES 1600000
#define D 64
#define NB 782                 // ceil(100000/128) dst-buckets of 128 nodes
#define CAP 3072               // slab slots per bucket (mean 2048, sigma~45)
#define EPB 8192               // edges per partition block
#define NPART ((N_EDGES + EPB - 1) / EPB)   // 196
#define RSH 14                 // src-range shift: range = src>>14 in 0..6

typedef unsigned short ushort_t;
typedef unsigned int uint_t;

// ---------- K1: repack feat -> bf16 (RNE) + init gcur ----------
__device__ __forceinline__ ushort_t f2bf(float f) {
    uint_t u = __float_as_uint(f);
    u += 0x7FFF + ((u >> 16) & 1);          // round-nearest-even
    return (ushort_t)(u >> 16);
}

__global__ __launch_bounds__(256) void repack_init(const float* __restrict__ feat,
                                                   ushort_t* __restrict__ featb,
                                                   int* __restrict__ gcur) {
    const int tid = blockIdx.x * 256 + threadIdx.x;
    if (tid < NB) gcur[tid] = tid * CAP;
    const int base = tid * 16;              // 16 floats per thread
    if (base >= N_NODES * D) return;
    const float4* f4 = (const float4*)(feat + base);
    ushort4* o4 = (ushort4*)(featb + base);
#pragma unroll
    for (int j = 0; j < 4; ++j) {
        const float4 v = f4[j];
        o4[j] = make_ushort4(f2bf(v.x), f2bf(v.y), f2bf(v.z), f2bf(v.w));
    }
}

// ---------- K2: partition edges into per-bucket slabs ----------
__global__ __launch_bounds__(1024) void partition(const int* __restrict__ esrc,
                                                  const int* __restrict__ edst,
                                                  int* __restrict__ gcur,
                                                  int* __restrict__ slab) {
    __shared__ int stage[EPB];              // 32 KB: packed, sorted by bucket
    __shared__ ushort_t bkt16[EPB];         // 16 KB: bucket of sorted pos
    __shared__ int cnt[NB];
    __shared__ int cur[NB];
    __shared__ int gb[NB];
    __shared__ int s[1024];
    const int t = threadIdx.x;
    const int base = blockIdx.x * EPB;
    const int n = min(EPB, N_EDGES - base);

    if (t < NB) cnt[t] = 0;
    __syncthreads();
    for (int i = t; i < n; i += 1024)
        atomicAdd(&cnt[edst[base + i] >> 7], 1);
    __syncthreads();
    const int v = (t < NB) ? cnt[t] : 0;
    s[t] = v;
    __syncthreads();
    for (int off = 1; off < 1024; off <<= 1) {
        const int x = (t >= off) ? s[t - off] : 0;
        __syncthreads();
        s[t] += x;
        __syncthreads();
    }
    if (t < NB) {
        const int excl = s[t] - v;          // exclusive prefix
        cur[t] = excl;
        gb[t] = (v ? atomicAdd(&gcur[t], v) : 0) - excl;
    }
    __syncthreads();
    for (int i = t; i < n; i += 1024) {     // coalesced re-read (L2-hot)
        const int d = edst[base + i];
        const int bkt = d >> 7;
        const int pos = atomicAdd(&cur[bkt], 1);
        stage[pos] = ((d & 127) << 17) | esrc[base + i];
        bkt16[pos] = (ushort_t)bkt;
    }
    __syncthreads();
    for (int i = t; i < n; i += 1024) {     // coalesced segment writes
        const int bkt = bkt16[i];
        const int gp = gb[bkt] + i;
        if (gp < (bkt + 1) * CAP)           // overflow guard (never expected)
            slab[gp] = stage[i];
    }
}

// ---------- 8-lane all-reduce on the VALU pipe (DPP, no DS ops) ----------
template<int CTRL>
__device__ __forceinline__ float fadd_dpp(float x) {
    const int r = __builtin_amdgcn_update_dpp(0, __float_as_int(x), CTRL, 0xF, 0xF, true);
    return x + __int_as_float(r);
}
__device__ __forceinline__ float red8(float p) {
    p = fadd_dpp<0xB1>(p);    // quad_perm [1,0,3,2]  : xor 1
    p = fadd_dpp<0x4E>(p);    // quad_perm [2,3,0,1]  : xor 2
    p = fadd_dpp<0x141>(p);   // row_half_mirror      : xor within 8
    return p;
}

// cvt 8 bf16 (uint4) -> g[8] fp32, and dot vs h[8]
__device__ __forceinline__ float cvt_dot(const uint4 u, const float* __restrict__ h,
                                         float* __restrict__ g) {
    g[0] = __uint_as_float(u.x << 16); g[1] = __uint_as_float(u.x & 0xFFFF0000u);
    g[2] = __uint_as_float(u.y << 16); g[3] = __uint_as_float(u.y & 0xFFFF0000u);
    g[4] = __uint_as_float(u.z << 16); g[5] = __uint_as_float(u.z & 0xFFFF0000u);
    g[6] = __uint_as_float(u.w << 16); g[7] = __uint_as_float(u.w & 0xFFFF0000u);
    float p = 0.f;
#pragma unroll
    for (int k = 0; k < 8; ++k) p += g[k] * h[k];
    return p;
}

// ---------- K3: fused SDDMM + SpMM ----------
// Round-0 structure. ONE change: 2-deep software pipeline in the quad loop --
// the next quad's 4 featb gathers are issued BEFORE the current quad's VALU
// block, doubling outstanding loads per thread (8 vs 4) to hide L2 latency.
// Costs +16 VGPR (v0..v3); predicted ~56, under the 64-VGPR occupancy cliff.
__global__ __launch_bounds__(512) void fused_spmm(const float4* __restrict__ feat4,
                                                  const uint4* __restrict__ featb4,
                                                  const int* __restrict__ slab,
                                                  const int* __restrict__ gcur,
                                                  float4* __restrict__ neigh4) {
    __shared__ int seA[CAP];                // 12 KB: raw packed (slab cache)
    __shared__ int seB[CAP];                // 12 KB: srcs sorted by (dst,rng)
    __shared__ int cnt[1024];
    __shared__ int cur[1024];
    __shared__ int rowoff[129];
    __shared__ int s[512];
    const int t = threadIdx.x;
    const int b = blockIdx.x;
    const int nbase = b << 7;
    const int nb_nodes = min(128, N_NODES - nbase);
    const int sbase = b * CAP;
    const int ne = min(gcur[b] - sbase, CAP);

    for (int i = t; i < ne; i += 512) seA[i] = slab[sbase + i];
    cnt[t] = 0; cnt[t + 512] = 0;
    __syncthreads();
    for (int i = t; i < ne; i += 512) {
        const int pk = seA[i];
        atomicAdd(&cnt[((pk >> 17) << 3) | ((pk & 0x1FFFF) >> RSH)], 1);
    }
    __syncthreads();
    const int v0 = cnt[2 * t], v1 = cnt[2 * t + 1];
    const int sum = v0 + v1;
    s[t] = sum;
    __syncthreads();
    for (int off = 1; off < 512; off <<= 1) {
        const int x = (t >= off) ? s[t - off] : 0;
        __syncthreads();
        s[t] += x;
        __syncthreads();
    }
    const int excl = s[t] - sum;
    cur[2 * t] = excl;
    cur[2 * t + 1] = excl + v0;
    __syncthreads();
    if (t < 128) rowoff[t] = cur[t << 3];
    if (t == 0) rowoff[128] = ne;
    __syncthreads();
    for (int i = t; i < ne; i += 512) {
        const int pk = seA[i];
        const int key = ((pk >> 17) << 3) | ((pk & 0x1FFFF) >> RSH);
        const int pos = atomicAdd(&cur[key], 1);
        seB[pos] = pk & 0x1FFFF;
    }
    __syncthreads();

    const int slot = t >> 3;                // 64 node-slots per block
    const int l = t & 7;                    // lane owns dims 8l..8l+7
#pragma unroll
    for (int ln0 = 0; ln0 < 128; ln0 += 64) {
        const int ln = ln0 + slot;
        if (ln >= nb_nodes) continue;       // no barriers below: safe
        const int nidx = nbase + ln;
        float h[8];
        {
            const float4 ha = feat4[nidx * 16 + 2 * l];
            const float4 hb = feat4[nidx * 16 + 2 * l + 1];
            h[0] = ha.x; h[1] = ha.y; h[2] = ha.z; h[3] = ha.w;
            h[4] = hb.x; h[5] = hb.y; h[6] = hb.z; h[7] = hb.w;
        }
        float acc[8];
#pragma unroll
        for (int k = 0; k < 8; ++k) acc[k] = 0.f;

        int e = rowoff[ln];
        const int e1 = rowoff[ln + 1];
        const int nq = (e1 - e) >> 2;       // number of full quads
        if (nq > 0) {
            // prologue: issue quad 0
            int s0 = seB[e], s1 = seB[e + 1], s2 = seB[e + 2], s3 = seB[e + 3];
            uint4 u0 = featb4[s0 * 8 + l];
            uint4 u1 = featb4[s1 * 8 + l];
            uint4 u2 = featb4[s2 * 8 + l];
            uint4 u3 = featb4[s3 * 8 + l];
            for (int q = 1; q < nq; ++q) {
                // issue quad q BEFORE processing quad q-1 (8 loads in flight)
                const int eb = e + q * 4;
                const int t0 = seB[eb], t1 = seB[eb + 1];
                const int t2 = seB[eb + 2], t3 = seB[eb + 3];
                const uint4 w0 = featb4[t0 * 8 + l];
                const uint4 w1 = featb4[t1 * 8 + l];
                const uint4 w2 = featb4[t2 * 8 + l];
                const uint4 w3 = featb4[t3 * 8 + l];
                float g0[8], g1[8], g2[8], g3[8];
                float p0 = cvt_dot(u0, h, g0);
                float p1 = cvt_dot(u1, h, g1);
                float p2 = cvt_dot(u2, h, g2);
                float p3 = cvt_dot(u3, h, g3);
                p0 = red8(p0); p1 = red8(p1); p2 = red8(p2); p3 = red8(p3);
#pragma unroll
                for (int k = 0; k < 8; ++k)
                    acc[k] += g0[k] * p0 + g1[k] * p1 + g2[k] * p2 + g3[k] * p3;
                u0 = w0; u1 = w1; u2 = w2; u3 = w3;
            }
            {   // epilogue: process final quad
                float g0[8], g1[8], g2[8], g3[8];
                float p0 = cvt_dot(u0, h, g0);
                float p1 = cvt_dot(u1, h, g1);
                float p2 = cvt_dot(u2, h, g2);
                float p3 = cvt_dot(u3, h, g3);
                p0 = red8(p0); p1 = red8(p1); p2 = red8(p2); p3 = red8(p3);
#pragma unroll
                for (int k = 0; k < 8; ++k)
                    acc[k] += g0[k] * p0 + g1[k] * p1 + g2[k] * p2 + g3[k] * p3;
            }
            e += nq * 4;
        }
        for (; e < e1; ++e) {
            const uint4 u0 = featb4[seB[e] * 8 + l];
            float g0[8];
            float p0 = red8(cvt_dot(u0, h, g0));
#pragma unroll
            for (int k = 0; k < 8; ++k) acc[k] += g0[k] * p0;
        }
        neigh4[nidx * 16 + 2 * l]     = make_float4(acc[0], acc[1], acc[2], acc[3]);
        neigh4[nidx * 16 + 2 * l + 1] = make_float4(acc[4], acc[5], acc[6], acc[7]);
    }
}

// ---------- K4: in-place GEMM out[n,:] = out[n,:] @ W^T ----------
__global__ __launch_bounds__(256) void gemm_inplace(float* __restrict__ out,
                                                    const float* __restrict__ W) {
    __shared__ float WT[64][68];
    __shared__ float nT[64][132];
    const int t = threadIdx.x;

    const float4* W4 = (const float4*)W;
#pragma unroll
    for (int j = 0; j < 4; ++j) {
        const int f = t + j * 256;
        const int o = f >> 4;
        const int i4 = (f & 15) * 4;
        const float4 w = W4[f];
        WT[i4 + 0][o] = w.x;
        WT[i4 + 1][o] = w.y;
        WT[i4 + 2][o] = w.z;
        WT[i4 + 3][o] = w.w;
    }

    const int base = blockIdx.x * 128;
    const int rows = min(128, N_NODES - base);
    const float4* O4 = (const float4*)(out + (long)base * D);
#pragma unroll
    for (int j = 0; j < 8; ++j) {
        const int f = t + j * 256;
        const int r = f >> 4;
        const int i4 = (f & 15) * 4;
        if (r < rows) {
            const float4 x = O4[f];
            nT[i4 + 0][r] = x.x;
            nT[i4 + 1][r] = x.y;
            nT[i4 + 2][r] = x.z;
            nT[i4 + 3][r] = x.w;
        }
    }
    __syncthreads();

    const int c4 = (t & 15) * 4;
    const int r0 = (t >> 4) * 8;
    float acc[8][4];
#pragma unroll
    for (int r = 0; r < 8; ++r)
#pragma unroll
        for (int c = 0; c < 4; ++c) acc[r][c] = 0.f;

    for (int i = 0; i < 64; ++i) {
        const float4 w = *(const float4*)&WT[i][c4];
        const float4 ra = *(const float4*)&nT[i][r0];
        const float4 rb = *(const float4*)&nT[i][r0 + 4];
        const float wv[4] = {w.x, w.y, w.z, w.w};
        const float rv[8] = {ra.x, ra.y, ra.z, ra.w, rb.x, rb.y, rb.z, rb.w};
#pragma unroll
        for (int r = 0; r < 8; ++r)
#pragma unroll
            for (int c = 0; c < 4; ++c) acc[r][c] += rv[r] * wv[c];
    }

#pragma unroll
    for (int r = 0; r < 8; ++r) {
        const int rr = r0 + r;
        if (rr < rows)
            *(float4*)&out[(long)(base + rr) * D + c4] =
                make_float4(acc[r][0], acc[r][1], acc[r][2], acc[r][3]);
    }
}

extern "C" void kernel_launch(void* const* d_in, const int* in_sizes, int n_in,
                              void* d_out, int out_size, void* d_ws, size_t ws_size,
                              hipStream_t stream) {
    const float* feat = (const float*)d_in[0];
    const int*   esrc = (const int*)d_in[1];
    const int*   edst = (const int*)d_in[2];
    const float* W    = (const float*)d_in[3];
    float* out = (float*)d_out;

    char* ws = (char*)d_ws;
    ushort_t* featb = (ushort_t*)(ws);                       // 12.8 MB
    int* slab = (int*)(ws + 12800000);                       // NB*CAP*4 = 9.61 MB
    int* gcur = (int*)(ws + 12800000 + (size_t)NB * CAP * 4);// 3.1 KB

    repack_init<<<(N_NODES * D / 16 + 255) / 256, 256, 0, stream>>>(feat, featb, gcur);
    partition<<<NPART, 1024, 0, stream>>>(esrc, edst, gcur, slab);
    fused_spmm<<<NB, 512, 0, stream>>>((const float4*)feat, (const uint4*)featb,
                                       slab, gcur, (float4*)out);
    gemm_inplace<<<(N_NODES + 127) / 128, 256, 0, stream>>>(out, W);
}